// Round 8
// baseline (1270.593 us; speedup 1.0000x reference)
//
#include <hip/hip_runtime.h>

#define NEG_SLOPE 0.01f
#define GN_EPS 1e-5f

typedef __attribute__((ext_vector_type(8))) __bf16 bf16x8;
typedef __attribute__((ext_vector_type(4))) __bf16 bf16x4;
typedef __attribute__((ext_vector_type(4))) float f32x4;
typedef __attribute__((ext_vector_type(2))) unsigned uintx2;

__device__ __forceinline__ float bf_lo(unsigned v) { return __uint_as_float(v << 16); }
__device__ __forceinline__ float bf_hi(unsigned v) { return __uint_as_float(v & 0xffff0000u); }
__device__ __forceinline__ unsigned pack_bf(float lo, float hi) {
    __bf16 a = (__bf16)lo, b = (__bf16)hi;
    unsigned short ua, ub;
    __builtin_memcpy(&ua, &a, 2); __builtin_memcpy(&ub, &b, 2);
    return (unsigned)ua | ((unsigned)ub << 16);
}

// ===========================================================================
// CSR build: histogram -> 2-level exclusive scan -> inverse-permutation scatter
// ===========================================================================
__global__ __launch_bounds__(256) void hist_kernel(
    const int* __restrict__ om, int* __restrict__ cnt, int E)
{
    const int stride = gridDim.x * blockDim.x;
    for (int e = blockIdx.x * blockDim.x + threadIdx.x; e < E; e += stride)
        atomicAdd(&cnt[om[e]], 1);
}

__global__ __launch_bounds__(256) void scan1_kernel(
    const int* __restrict__ cnt, int* __restrict__ part, int N)
{
    __shared__ int ls[256];
    int b = blockIdx.x, t = threadIdx.x;
    int i0 = b * 1024 + t * 4, s = 0;
#pragma unroll
    for (int u = 0; u < 4; ++u) if (i0 + u < N) s += cnt[i0 + u];
    ls[t] = s; __syncthreads();
    for (int off = 128; off > 0; off >>= 1) {
        if (t < off) ls[t] += ls[t + off];
        __syncthreads();
    }
    if (t == 0) part[b] = ls[0];
}

__global__ void scan2_kernel(int* __restrict__ part, int nb)
{
    if (blockIdx.x == 0 && threadIdx.x == 0) {
        int run = 0;
        for (int i = 0; i < nb; ++i) { int v = part[i]; part[i] = run; run += v; }
    }
}

__global__ __launch_bounds__(256) void scan3_kernel(
    const int* __restrict__ cnt, const int* __restrict__ part,
    int* __restrict__ base, int N)
{
    __shared__ int ls[256];
    int b = blockIdx.x, t = threadIdx.x;
    int i0 = b * 1024 + t * 4;
    int v0 = 0, v1 = 0, v2 = 0, v3 = 0;
    if (i0 + 0 < N) v0 = cnt[i0 + 0];
    if (i0 + 1 < N) v1 = cnt[i0 + 1];
    if (i0 + 2 < N) v2 = cnt[i0 + 2];
    if (i0 + 3 < N) v3 = cnt[i0 + 3];
    int s = v0 + v1 + v2 + v3;
    ls[t] = s; __syncthreads();
    for (int off = 1; off < 256; off <<= 1) {
        int x = (t >= off) ? ls[t - off] : 0;
        __syncthreads();
        ls[t] += x;
        __syncthreads();
    }
    int run = part[b] + ls[t] - s;   // exclusive prefix
    if (i0 + 0 < N) { base[i0 + 0] = run; run += v0; if (i0 + 0 == N - 1) base[N] = run; }
    if (i0 + 1 < N) { base[i0 + 1] = run; run += v1; if (i0 + 1 == N - 1) base[N] = run; }
    if (i0 + 2 < N) { base[i0 + 2] = run; run += v2; if (i0 + 2 == N - 1) base[N] = run; }
    if (i0 + 3 < N) { base[i0 + 3] = run; run += v3; if (i0 + 3 == N - 1) base[N] = run; }
}

__global__ __launch_bounds__(256) void scatter_kernel(
    const int* __restrict__ om, const int* __restrict__ base,
    int* __restrict__ cur, int* __restrict__ inv, int E)
{
    const int stride = gridDim.x * blockDim.x;
    for (int e = blockIdx.x * blockDim.x + threadIdx.x; e < E; e += stride) {
        int o = om[e];
        int p = base[o] + atomicAdd(&cur[o], 1);
        inv[e] = p;           // edge e's row lands at sorted position p
    }
}

// ===========================================================================
// Phase A: per-offset GEMM via bf16 MFMA, OPERAND-SWAPPED: D = W^T · feats^T
// so D row = channel, col = edge. Each lane then owns 4 CONSECUTIVE channels
// (nt*16+lg*4+r) of edge l15 -> pack 2x uint -> 8B stores (vs 16x 2B scalar
// stores in the unswapped form). A/B fragments have identical lane mappings,
// so the feats gather and Wfrag layout are unchanged; C layout [p][64] same.
// C row for edge e goes to sorted position inv[e]; non-temporal (read once).
// ===========================================================================
template<int F32IN>
__global__ __launch_bounds__(256) void conv_mfma_kernel(
    const void* __restrict__ feats, const float* __restrict__ W,
    const int* __restrict__ in_map, const int* __restrict__ inv,
    __bf16* __restrict__ C, int M, int BPK)
{
    const int lane = threadIdx.x & 63;
    const int wv   = threadIdx.x >> 6;
    const int k    = blockIdx.x / BPK;
    const int blk  = blockIdx.x % BPK;
    const int l15  = lane & 15;
    const int lg   = lane >> 4;         // 0..3

    // W fragments (now the A operand): w[nt][h] = W[c=h*32+lg*8+j][d=nt*16+l15]
    const float* Wk = W + (size_t)k * 4096;
    bf16x8 w[4][2];
#pragma unroll
    for (int nt = 0; nt < 4; ++nt)
#pragma unroll
        for (int h = 0; h < 2; ++h)
#pragma unroll
            for (int j = 0; j < 8; ++j)
                w[nt][h][j] = (__bf16)Wk[(h * 32 + lg * 8 + j) * 64 + nt * 16 + l15];

    const int* imk   = in_map + (size_t)k * M;
    const int ntiles = (M + 15) >> 4;
    const int wpk    = BPK * 4;

    for (int t = blk * 4 + wv; t < ntiles; t += wpk) {
        const int m     = t * 16 + l15;
        const bool valid = m < M;
        const int mc    = valid ? m : M - 1;
        const int ii    = imk[mc];
        bf16x8 a0, a1;                    // feats fragments (B operand)
        if (F32IN) {
            const float4* rp = (const float4*)((const float*)feats + (size_t)ii * 64 + lg * 8);
            float4 u0 = rp[0], u1 = rp[1];
            float4 u2 = rp[8], u3 = rp[9];   // +32 channels
            a0[0] = (__bf16)u0.x; a0[1] = (__bf16)u0.y; a0[2] = (__bf16)u0.z; a0[3] = (__bf16)u0.w;
            a0[4] = (__bf16)u1.x; a0[5] = (__bf16)u1.y; a0[6] = (__bf16)u1.z; a0[7] = (__bf16)u1.w;
            a1[0] = (__bf16)u2.x; a1[1] = (__bf16)u2.y; a1[2] = (__bf16)u2.z; a1[3] = (__bf16)u2.w;
            a1[4] = (__bf16)u3.x; a1[5] = (__bf16)u3.y; a1[6] = (__bf16)u3.z; a1[7] = (__bf16)u3.w;
        } else {
            const bf16x8* rp = (const bf16x8*)((const __bf16*)feats + (size_t)ii * 64 + lg * 8);
            a0 = rp[0];
            a1 = rp[4];   // +32 channels
        }
        f32x4 c0 = {0.f,0.f,0.f,0.f}, c1 = c0, c2 = c0, c3 = c0;
        c0 = __builtin_amdgcn_mfma_f32_16x16x32_bf16(w[0][0], a0, c0, 0, 0, 0);
        c1 = __builtin_amdgcn_mfma_f32_16x16x32_bf16(w[1][0], a0, c1, 0, 0, 0);
        c2 = __builtin_amdgcn_mfma_f32_16x16x32_bf16(w[2][0], a0, c2, 0, 0, 0);
        c3 = __builtin_amdgcn_mfma_f32_16x16x32_bf16(w[3][0], a0, c3, 0, 0, 0);
        c0 = __builtin_amdgcn_mfma_f32_16x16x32_bf16(w[0][1], a1, c0, 0, 0, 0);
        c1 = __builtin_amdgcn_mfma_f32_16x16x32_bf16(w[1][1], a1, c1, 0, 0, 0);
        c2 = __builtin_amdgcn_mfma_f32_16x16x32_bf16(w[2][1], a1, c2, 0, 0, 0);
        c3 = __builtin_amdgcn_mfma_f32_16x16x32_bf16(w[3][1], a1, c3, 0, 0, 0);

        // D[row=channel nt*16+lg*4+r][col=edge l15]
        const int p = inv[(size_t)k * M + mc];   // per-lane, coalesced
        if (valid) {
            unsigned* cr = (unsigned*)(C + (size_t)p * 64 + lg * 4);
            f32x4 cc[4] = {c0, c1, c2, c3};
#pragma unroll
            for (int nt = 0; nt < 4; ++nt) {
                uintx2 u = {pack_bf(cc[nt][0], cc[nt][1]),
                            pack_bf(cc[nt][2], cc[nt][3])};
                __builtin_nontemporal_store(u, (uintx2*)(cr + nt * 8));
            }
        }
    }
}

// ===========================================================================
// Phase B: segmented streaming reduce + FUSED GroupNorm stats. Grid-stride:
// one wave per output row per iter; C rows for output o are contiguous
// [base[o], base[o+1]). 2 rows/iter: lane = (row parity)<<5 | channel-pair.
// Per-wave stat registers -> block LDS combine -> 16 global atomics/block.
// ===========================================================================
__global__ __launch_bounds__(256) void reduce_kernel(
    const unsigned short* __restrict__ C, const int* __restrict__ base,
    float* __restrict__ out, float* __restrict__ stats, int N)
{
    const int lane = threadIdx.x & 63;
    const int wv   = threadIdx.x >> 6;
    const int c2   = lane & 31;       // channel pair index (channels 2c2, 2c2+1)
    const int half = lane >> 5;       // row parity
    float rs = 0.f, rq = 0.f;

    const int ostride = gridDim.x * 4;
    for (int o = blockIdx.x * 4 + wv; o < N; o += ostride) {
        const int s = base[o], t = base[o + 1];
        float s0 = 0.f, s1 = 0.f;
        for (int i = s + half; i < t; i += 2) {
            unsigned v = __builtin_nontemporal_load(
                (const unsigned*)(C + (size_t)i * 64 + c2 * 2));
            s0 += bf_lo(v);
            s1 += bf_hi(v);
        }
        s0 += __shfl_xor(s0, 32);
        s1 += __shfl_xor(s1, 32);
        if (half == 0) {
            float2 r = {s0, s1};
            *(float2*)(out + (size_t)o * 64 + c2 * 2) = r;
            rs += s0 + s1;                    // both channels in group c2>>2
            rq += s0 * s0 + s1 * s1;
        }
    }
    // combine lanes of the same group g = c2>>2 (xor 1,2 stays within half)
    rs += __shfl_xor(rs, 1); rq += __shfl_xor(rq, 1);
    rs += __shfl_xor(rs, 2); rq += __shfl_xor(rq, 2);
    __shared__ float ls[4][16];
    const int g = c2 >> 2;
    if (half == 0 && (c2 & 3) == 0) { ls[wv][g] = rs; ls[wv][8 + g] = rq; }
    __syncthreads();
    if (threadIdx.x < 16) {
        float t = (ls[0][threadIdx.x] + ls[1][threadIdx.x]) +
                  (ls[2][threadIdx.x] + ls[3][threadIdx.x]);
        unsafeAtomicAdd(stats + threadIdx.x, t);
    }
}

// ===========================================================================
// Legacy atomic-scatter conv + standalone gn_stats (ws_size fallback path)
// ===========================================================================
__global__ __launch_bounds__(256) void conv_kernel(
    const float* __restrict__ feats, const float* __restrict__ W,
    const int* __restrict__ in_map, const int* __restrict__ out_map,
    float* __restrict__ out, int M, int BPK)
{
    const int lane = threadIdx.x & 63;
    const int wv   = threadIdx.x >> 6;
    const int k    = blockIdx.x / BPK;
    const int blk  = blockIdx.x % BPK;
    const float* Wk = W + (size_t)k * 4096;
    float w[64];
#pragma unroll
    for (int c = 0; c < 64; ++c) w[c] = Wk[c * 64 + lane];
    __shared__ float fbuf[4][64];
    const int* im = in_map + (size_t)k * M;
    const int* om = out_map + (size_t)k * M;
    const int stride = BPK * 4;
    for (int m = blk * 4 + wv; m < M; m += stride) {
        int ii = im[m];
        int oi = om[m];
        float f = feats[(size_t)ii * 64 + lane];
        fbuf[wv][lane] = f;
        const float* fb = fbuf[wv];
        float a0 = 0.f, a1 = 0.f, a2 = 0.f, a3 = 0.f;
#pragma unroll
        for (int c = 0; c < 64; c += 4) {
            float4 f4 = *(const float4*)(fb + c);
            a0 = fmaf(f4.x, w[c + 0], a0);
            a1 = fmaf(f4.y, w[c + 1], a1);
            a2 = fmaf(f4.z, w[c + 2], a2);
            a3 = fmaf(f4.w, w[c + 3], a3);
        }
        unsafeAtomicAdd(out + (size_t)oi * 64 + lane, (a0 + a1) + (a2 + a3));
    }
}

__global__ __launch_bounds__(256) void gn_stats_kernel(
    const float4* __restrict__ x, float* __restrict__ stats, long total4)
{
    const int lane = threadIdx.x & 63;
    float s = 0.f, q = 0.f;
    const long stride = (long)gridDim.x * blockDim.x;
    for (long i = (long)blockIdx.x * blockDim.x + threadIdx.x; i < total4; i += stride) {
        float4 v = x[i];
        s += (v.x + v.y) + (v.z + v.w);
        q += (v.x * v.x + v.y * v.y) + (v.z * v.z + v.w * v.w);
    }
    s += __shfl_xor(s, 1);  q += __shfl_xor(q, 1);
    s += __shfl_xor(s, 16); q += __shfl_xor(q, 16);
    s += __shfl_xor(s, 32); q += __shfl_xor(q, 32);
    __shared__ float ls[4][16];
    const int wv = threadIdx.x >> 6;
    const int g = (lane >> 1) & 7;
    if (lane < 16 && (lane & 1) == 0) { ls[wv][g] = s; ls[wv][8 + g] = q; }
    __syncthreads();
    if (threadIdx.x < 16) {
        float t = (ls[0][threadIdx.x] + ls[1][threadIdx.x]) +
                  (ls[2][threadIdx.x] + ls[3][threadIdx.x]);
        unsafeAtomicAdd(stats + threadIdx.x, t);
    }
}

// ===========================================================================
// GroupNorm apply (+residual, +leaky); fp32 and/or bf16 outputs.
// ===========================================================================
__global__ __launch_bounds__(256) void gn_apply_kernel(
    const float4* __restrict__ x, const float* __restrict__ stats,
    const float* __restrict__ gamma, const float* __restrict__ beta,
    const float4* resid, float4* out_f, bf16x4* out_bf,
    long total4, float invc, int do_leaky)
{
    __shared__ float sc[64], sh[64];
    if (threadIdx.x < 64) {
        int c = threadIdx.x, g = c >> 3;
        float mean = stats[g] * invc;
        float var  = fmaf(-mean, mean, stats[8 + g] * invc);
        float s    = rsqrtf(var + GN_EPS) * gamma[c];
        sc[c] = s;
        sh[c] = fmaf(-mean, s, beta[c]);
    }
    __syncthreads();
    const long stride = (long)gridDim.x * blockDim.x;
    for (long i = (long)blockIdx.x * blockDim.x + threadIdx.x; i < total4; i += stride) {
        float4 v = x[i];
        int c0 = ((int)(i & 15)) << 2;
        float4 r;
        r.x = fmaf(v.x, sc[c0 + 0], sh[c0 + 0]);
        r.y = fmaf(v.y, sc[c0 + 1], sh[c0 + 1]);
        r.z = fmaf(v.z, sc[c0 + 2], sh[c0 + 2]);
        r.w = fmaf(v.w, sc[c0 + 3], sh[c0 + 3]);
        if (resid) {
            float4 h4 = resid[i];
            r.x += h4.x; r.y += h4.y; r.z += h4.z; r.w += h4.w;
        }
        if (do_leaky) {
            r.x = r.x >= 0.f ? r.x : NEG_SLOPE * r.x;
            r.y = r.y >= 0.f ? r.y : NEG_SLOPE * r.y;
            r.z = r.z >= 0.f ? r.z : NEG_SLOPE * r.z;
            r.w = r.w >= 0.f ? r.w : NEG_SLOPE * r.w;
        }
        if (out_f) out_f[i] = r;
        if (out_bf) {
            bf16x4 o;
            o.x = (__bf16)r.x; o.y = (__bf16)r.y; o.z = (__bf16)r.z; o.w = (__bf16)r.w;
            out_bf[i] = o;
        }
    }
}

// ===========================================================================
extern "C" void kernel_launch(void* const* d_in, const int* in_sizes, int n_in,
                              void* d_out, int out_size, void* d_ws, size_t ws_size,
                              hipStream_t stream) {
    const float* x   = (const float*)d_in[0];
    const float* W1  = (const float*)d_in[1];
    const float* g1  = (const float*)d_in[2];
    const float* b1  = (const float*)d_in[3];
    const float* Wa1 = (const float*)d_in[4];
    const float* ga1 = (const float*)d_in[5];
    const float* ba1 = (const float*)d_in[6];
    const float* Wb1 = (const float*)d_in[7];
    const float* gb1 = (const float*)d_in[8];
    const float* bb1 = (const float*)d_in[9];
    const float* Wa2 = (const float*)d_in[10];
    const float* ga2 = (const float*)d_in[11];
    const float* ba2 = (const float*)d_in[12];
    const float* Wb2 = (const float*)d_in[13];
    const float* gb2 = (const float*)d_in[14];
    const float* bb2 = (const float*)d_in[15];
    const int* m1_in  = (const int*)d_in[16];
    const int* m1_out = (const int*)d_in[17];
    const int* m2_in  = (const int*)d_in[18];
    const int* m2_out = (const int*)d_in[19];

    const int N   = out_size / 64;
    const int M1  = in_sizes[16] / 8;
    const int M2  = in_sizes[18] / 27;
    const int E1  = 8 * M1;
    const int E2  = 27 * M2;
    const int Emax = E1 > E2 ? E1 : E2;

    float* h = (float*)d_out;
    const long  total4 = (long)N * 16;
    const float invc   = 1.f / ((float)N * 8.f);

    // ---- workspace layout (256B aligned) ----
    char* wp = (char*)d_ws;
    size_t off = 0;
    auto alloc = [&](size_t bytes) {
        void* p = wp + off;
        off = (off + bytes + 255) & ~(size_t)255;
        return p;
    };
    float*  acc   = (float*)alloc((size_t)N * 64 * 4);
    __bf16* hbf   = (__bf16*)alloc((size_t)N * 64 * 2);
    __bf16* ybf   = (__bf16*)alloc((size_t)N * 64 * 2);
    __bf16* Cbuf  = (__bf16*)alloc((size_t)Emax * 64 * 2);
    int*    base1 = (int*)alloc((size_t)(N + 1) * 4);
    int*    base2 = (int*)alloc((size_t)(N + 1) * 4);
    int*    cnt   = (int*)alloc((size_t)N * 4);
    int*    part  = (int*)alloc(4096);
    int*    inv1  = (int*)alloc((size_t)E1 * 4);
    int*    inv2  = (int*)alloc((size_t)E2 * 4);
    float*  stats = (float*)alloc(64);
    const size_t need = off;

    if (ws_size < need) {
        // -------- legacy atomic fallback --------
        float* y  = acc + (size_t)N * 64;
        float* st = y + (size_t)N * 64;
        const size_t nbytes = (size_t)N * 64 * 4;
        auto convL = [&](const float* feats, const float* W, const int* im,
                         const int* om, int K, int M, int BPK) {
            hipMemsetAsync(acc, 0, nbytes, stream);
            conv_kernel<<<dim3(K * BPK), 256, 0, stream>>>(feats, W, im, om, acc, M, BPK);
        };
        auto gnL = [&](const float* gamma, const float* beta, const float* resid,
                       float* outp, int leaky) {
            hipMemsetAsync(st, 0, 16 * sizeof(float), stream);
            gn_stats_kernel<<<1024, 256, 0, stream>>>((const float4*)acc, st, total4);
            gn_apply_kernel<<<1024, 256, 0, stream>>>((const float4*)acc, st, gamma, beta,
                                                      (const float4*)resid, (float4*)outp,
                                                      nullptr, total4, invc, leaky);
        };
        convL(x, W1, m1_in, m1_out, 8, M1, 320); gnL(g1, b1, nullptr, h, 1);
        convL(h, Wa1, m2_in, m2_out, 27, M2, 96); gnL(ga1, ba1, nullptr, y, 0);
        convL(y, Wb1, m2_in, m2_out, 27, M2, 96); gnL(gb1, bb1, h, h, 1);
        convL(h, Wa2, m2_in, m2_out, 27, M2, 96); gnL(ga2, ba2, nullptr, y, 0);
        convL(y, Wb2, m2_in, m2_out, 27, M2, 96); gnL(gb2, bb2, h, h, 1);
        return;
    }

    // -------- MFMA + sorted-streaming-reduce path --------
    const int nb = (N + 1023) / 1024;
    auto buildCSR = [&](const int* om, int E, int* base, int* inv) {
        hipMemsetAsync(cnt, 0, (size_t)N * 4, stream);
        hist_kernel<<<2048, 256, 0, stream>>>(om, cnt, E);
        scan1_kernel<<<nb, 256, 0, stream>>>(cnt, part, N);
        scan2_kernel<<<1, 64, 0, stream>>>(part, nb);
        scan3_kernel<<<nb, 256, 0, stream>>>(cnt, part, base, N);
        hipMemsetAsync(cnt, 0, (size_t)N * 4, stream);
        scatter_kernel<<<2048, 256, 0, stream>>>(om, base, cnt, inv, E);
    };
    buildCSR(m1_out, E1, base1, inv1);
    buildCSR(m2_out, E2, base2, inv2);

    auto conv = [&](const void* feats, int f32in, const float* W, const int* im,
                    int K, int M, int BPK, const int* base, const int* inv) {
        hipMemsetAsync(stats, 0, 64, stream);
        if (f32in)
            conv_mfma_kernel<1><<<dim3(K * BPK), 256, 0, stream>>>(feats, W, im, inv, Cbuf, M, BPK);
        else
            conv_mfma_kernel<0><<<dim3(K * BPK), 256, 0, stream>>>(feats, W, im, inv, Cbuf, M, BPK);
        reduce_kernel<<<2048, 256, 0, stream>>>((const unsigned short*)Cbuf, base,
                                                acc, stats, N);
    };
    auto gn = [&](const float* gamma, const float* beta, const float* resid,
                  float* outf, __bf16* outbf, int leaky) {
        gn_apply_kernel<<<1024, 256, 0, stream>>>((const float4*)acc, stats, gamma, beta,
                                                  (const float4*)resid, (float4*)outf,
                                                  (bf16x4*)outbf, total4, invc, leaky);
    };

    // BasicConvolutionBlock (gathers fp32 x directly)
    conv(x, 1, W1, m1_in, 8, M1, 128, base1, inv1);
    gn(g1, b1, nullptr, h, hbf, 1);
    // ResidualBlock 1
    conv(hbf, 0, Wa1, m2_in, 27, M2, 64, base2, inv2);
    gn(ga1, ba1, nullptr, nullptr, ybf, 0);
    conv(ybf, 0, Wb1, m2_in, 27, M2, 64, base2, inv2);
    gn(gb1, bb1, h, h, hbf, 1);
    // ResidualBlock 2
    conv(hbf, 0, Wa2, m2_in, 27, M2, 64, base2, inv2);
    gn(ga2, ba2, nullptr, nullptr, ybf, 0);
    conv(ybf, 0, Wb2, m2_in, 27, M2, 64, base2, inv2);
    gn(gb2, bb2, h, h, hbf, 1);
}

// Round 9
// 1173.568 us; speedup vs baseline: 1.0827x; 1.0827x over previous
//
#include <hip/hip_runtime.h>

#define NEG_SLOPE 0.01f
#define GN_EPS 1e-5f

typedef __attribute__((ext_vector_type(8))) __bf16 bf16x8;
typedef __attribute__((ext_vector_type(4))) __bf16 bf16x4;
typedef __attribute__((ext_vector_type(4))) float f32x4;
typedef __attribute__((ext_vector_type(2))) unsigned uintx2;

__device__ __forceinline__ float bf_lo(unsigned v) { return __uint_as_float(v << 16); }
__device__ __forceinline__ float bf_hi(unsigned v) { return __uint_as_float(v & 0xffff0000u); }

// ===========================================================================
// CSR build: histogram -> 2-level exclusive scan -> inverse-permutation scatter
// ===========================================================================
__global__ __launch_bounds__(256) void hist_kernel(
    const int* __restrict__ om, int* __restrict__ cnt, int E)
{
    const int stride = gridDim.x * blockDim.x;
    for (int e = blockIdx.x * blockDim.x + threadIdx.x; e < E; e += stride)
        atomicAdd(&cnt[om[e]], 1);
}

__global__ __launch_bounds__(256) void scan1_kernel(
    const int* __restrict__ cnt, int* __restrict__ part, int N)
{
    __shared__ int ls[256];
    int b = blockIdx.x, t = threadIdx.x;
    int i0 = b * 1024 + t * 4, s = 0;
#pragma unroll
    for (int u = 0; u < 4; ++u) if (i0 + u < N) s += cnt[i0 + u];
    ls[t] = s; __syncthreads();
    for (int off = 128; off > 0; off >>= 1) {
        if (t < off) ls[t] += ls[t + off];
        __syncthreads();
    }
    if (t == 0) part[b] = ls[0];
}

__global__ void scan2_kernel(int* __restrict__ part, int nb)
{
    if (blockIdx.x == 0 && threadIdx.x == 0) {
        int run = 0;
        for (int i = 0; i < nb; ++i) { int v = part[i]; part[i] = run; run += v; }
    }
}

__global__ __launch_bounds__(256) void scan3_kernel(
    const int* __restrict__ cnt, const int* __restrict__ part,
    int* __restrict__ base, int N)
{
    __shared__ int ls[256];
    int b = blockIdx.x, t = threadIdx.x;
    int i0 = b * 1024 + t * 4;
    int v0 = 0, v1 = 0, v2 = 0, v3 = 0;
    if (i0 + 0 < N) v0 = cnt[i0 + 0];
    if (i0 + 1 < N) v1 = cnt[i0 + 1];
    if (i0 + 2 < N) v2 = cnt[i0 + 2];
    if (i0 + 3 < N) v3 = cnt[i0 + 3];
    int s = v0 + v1 + v2 + v3;
    ls[t] = s; __syncthreads();
    for (int off = 1; off < 256; off <<= 1) {
        int x = (t >= off) ? ls[t - off] : 0;
        __syncthreads();
        ls[t] += x;
        __syncthreads();
    }
    int run = part[b] + ls[t] - s;   // exclusive prefix
    if (i0 + 0 < N) { base[i0 + 0] = run; run += v0; if (i0 + 0 == N - 1) base[N] = run; }
    if (i0 + 1 < N) { base[i0 + 1] = run; run += v1; if (i0 + 1 == N - 1) base[N] = run; }
    if (i0 + 2 < N) { base[i0 + 2] = run; run += v2; if (i0 + 2 == N - 1) base[N] = run; }
    if (i0 + 3 < N) { base[i0 + 3] = run; run += v3; if (i0 + 3 == N - 1) base[N] = run; }
}

__global__ __launch_bounds__(256) void scatter_kernel(
    const int* __restrict__ om, const int* __restrict__ base,
    int* __restrict__ cur, int* __restrict__ inv, int E)
{
    const int stride = gridDim.x * blockDim.x;
    for (int e = blockIdx.x * blockDim.x + threadIdx.x; e < E; e += stride) {
        int o = om[e];
        int p = base[o] + atomicAdd(&cur[o], 1);
        inv[e] = p;           // edge e's row lands at sorted position p
    }
}

// ===========================================================================
// Phase A: per-offset GEMM via bf16 MFMA (round-7 orientation: D row=edge,
// col=channel; each lane-quarter emits its row as 4x32B back-to-back ->
// full-line merge, WRITE_SIZE == |C| exactly). C row for edge e goes to
// sorted position inv[e]; non-temporal (read once by reduce).
// NORM: gather applies GroupNorm scale/shift (from stats of the previous
// reduce) in-register -> the mid-residual y is never materialized.
// ===========================================================================
template<int F32IN, int NORM>
__global__ __launch_bounds__(256) void conv_mfma_kernel(
    const void* __restrict__ feats, const float* __restrict__ W,
    const int* __restrict__ in_map, const int* __restrict__ inv,
    __bf16* __restrict__ C, int M, int BPK,
    const float* __restrict__ stats, const float* __restrict__ gamma,
    const float* __restrict__ beta, float invc)
{
    const int lane = threadIdx.x & 63;
    const int wv   = threadIdx.x >> 6;
    const int k    = blockIdx.x / BPK;
    const int blk  = blockIdx.x % BPK;
    const int l15  = lane & 15;
    const int lg   = lane >> 4;         // 0..3

    // per-lane GN scale/shift for its 16 gather channels {hh*32+lg*8+j}
    float scv[2][8], shv[2][8];
    if (NORM) {
#pragma unroll
        for (int hh = 0; hh < 2; ++hh) {
            int g = hh * 4 + lg;
            float mean = stats[g] * invc;
            float var  = fmaf(-mean, mean, stats[8 + g] * invc);
            float rstd = rsqrtf(var + GN_EPS);
#pragma unroll
            for (int j = 0; j < 8; ++j) {
                int ch = hh * 32 + lg * 8 + j;
                float s = rstd * gamma[ch];
                scv[hh][j] = s;
                shv[hh][j] = fmaf(-mean, s, beta[ch]);
            }
        }
    }

    // B fragments: b[nt][h] covers cols nt*16+l15, K-half h
    const float* Wk = W + (size_t)k * 4096;
    bf16x8 b[4][2];
#pragma unroll
    for (int nt = 0; nt < 4; ++nt)
#pragma unroll
        for (int h = 0; h < 2; ++h)
#pragma unroll
            for (int j = 0; j < 8; ++j)
                b[nt][h][j] = (__bf16)Wk[(h * 32 + lg * 8 + j) * 64 + nt * 16 + l15];

    const int* imk   = in_map + (size_t)k * M;
    const int ntiles = (M + 15) >> 4;
    const int wpk    = BPK * 4;

    for (int t = blk * 4 + wv; t < ntiles; t += wpk) {
        int m  = t * 16 + l15;
        int mc = m < M ? m : M - 1;
        int ii = imk[mc];
        bf16x8 a0, a1;
        if (F32IN) {
            const float4* rp = (const float4*)((const float*)feats + (size_t)ii * 64 + lg * 8);
            float4 u0 = rp[0], u1 = rp[1];
            float4 u2 = rp[8], u3 = rp[9];   // +32 channels
            float lo[8] = {u0.x, u0.y, u0.z, u0.w, u1.x, u1.y, u1.z, u1.w};
            float hi[8] = {u2.x, u2.y, u2.z, u2.w, u3.x, u3.y, u3.z, u3.w};
#pragma unroll
            for (int j = 0; j < 8; ++j) {
                float v0 = lo[j], v1 = hi[j];
                if (NORM) {
                    v0 = fmaf(v0, scv[0][j], shv[0][j]);
                    v1 = fmaf(v1, scv[1][j], shv[1][j]);
                }
                a0[j] = (__bf16)v0;
                a1[j] = (__bf16)v1;
            }
        } else {
            const bf16x8* rp = (const bf16x8*)((const __bf16*)feats + (size_t)ii * 64 + lg * 8);
            a0 = rp[0];
            a1 = rp[4];   // +32 channels
        }
        f32x4 c0 = {0.f,0.f,0.f,0.f}, c1 = c0, c2 = c0, c3 = c0;
        c0 = __builtin_amdgcn_mfma_f32_16x16x32_bf16(a0, b[0][0], c0, 0, 0, 0);
        c1 = __builtin_amdgcn_mfma_f32_16x16x32_bf16(a0, b[1][0], c1, 0, 0, 0);
        c2 = __builtin_amdgcn_mfma_f32_16x16x32_bf16(a0, b[2][0], c2, 0, 0, 0);
        c3 = __builtin_amdgcn_mfma_f32_16x16x32_bf16(a0, b[3][0], c3, 0, 0, 0);
        c0 = __builtin_amdgcn_mfma_f32_16x16x32_bf16(a1, b[0][1], c0, 0, 0, 0);
        c1 = __builtin_amdgcn_mfma_f32_16x16x32_bf16(a1, b[1][1], c1, 0, 0, 0);
        c2 = __builtin_amdgcn_mfma_f32_16x16x32_bf16(a1, b[2][1], c2, 0, 0, 0);
        c3 = __builtin_amdgcn_mfma_f32_16x16x32_bf16(a1, b[3][1], c3, 0, 0, 0);

        const int e_base = k * M + t * 16;
        f32x4 cc[4] = {c0, c1, c2, c3};
#pragma unroll
        for (int r = 0; r < 4; ++r) {
            int row = lg * 4 + r;
            if (t * 16 + row < M) {
                int p = inv[e_base + row];            // broadcast within l15-group
                __bf16* cr = C + (size_t)p * 64 + l15;
#pragma unroll
                for (int nt = 0; nt < 4; ++nt) {
                    __bf16 v = (__bf16)cc[nt][r];
                    __builtin_nontemporal_store(v, cr + nt * 16);
                }
            }
        }
    }
}

// ===========================================================================
// Phase B: segmented streaming reduce + FUSED GroupNorm stats. One wave per
// output row per iter; 4 rows/instruction: lane = (row group l>>4) x
// (channel quad l&15, 8B uintx2 load). 16 lanes store float4 per row.
// Per-wave stat registers -> block LDS combine -> 16 global atomics/block.
// ===========================================================================
__global__ __launch_bounds__(256) void reduce_kernel(
    const unsigned* __restrict__ C2, const int* __restrict__ base,
    float* __restrict__ out, float* __restrict__ stats, int N)
{
    const int lane = threadIdx.x & 63;
    const int wv   = threadIdx.x >> 6;
    const int rq   = lane >> 4;       // row offset 0..3
    const int cq   = lane & 15;       // channel quad: channels cq*4 .. cq*4+3
    float rs = 0.f, rqsum = 0.f;

    const int ostride = gridDim.x * 4;
    for (int o = blockIdx.x * 4 + wv; o < N; o += ostride) {
        const int s = base[o], t = base[o + 1];
        float a0 = 0.f, a1 = 0.f, a2 = 0.f, a3 = 0.f;
        for (int i = s + rq; i < t; i += 4) {
            uintx2 v = __builtin_nontemporal_load(
                (const uintx2*)(C2 + (size_t)i * 32 + cq * 2));
            a0 += bf_lo(v.x); a1 += bf_hi(v.x);
            a2 += bf_lo(v.y); a3 += bf_hi(v.y);
        }
        a0 += __shfl_xor(a0, 16); a1 += __shfl_xor(a1, 16);
        a2 += __shfl_xor(a2, 16); a3 += __shfl_xor(a3, 16);
        a0 += __shfl_xor(a0, 32); a1 += __shfl_xor(a1, 32);
        a2 += __shfl_xor(a2, 32); a3 += __shfl_xor(a3, 32);
        if (rq == 0) {
            float4 r = {a0, a1, a2, a3};
            *(float4*)(out + (size_t)o * 64 + cq * 4) = r;
            rs    += (a0 + a1) + (a2 + a3);
            rqsum += (a0 * a0 + a1 * a1) + (a2 * a2 + a3 * a3);
        }
    }
    // lanes rq==0: channel quad cq belongs to group g = cq>>1; combine pairs
    rs += __shfl_xor(rs, 1); rqsum += __shfl_xor(rqsum, 1);
    __shared__ float ls[4][16];
    if (rq == 0 && (cq & 1) == 0) {
        ls[wv][cq >> 1] = rs;
        ls[wv][8 + (cq >> 1)] = rqsum;
    }
    __syncthreads();
    if (threadIdx.x < 16) {
        float t = (ls[0][threadIdx.x] + ls[1][threadIdx.x]) +
                  (ls[2][threadIdx.x] + ls[3][threadIdx.x]);
        unsafeAtomicAdd(stats + threadIdx.x, t);
    }
}

// ===========================================================================
// Legacy atomic-scatter conv + standalone gn_stats (ws_size fallback path)
// ===========================================================================
__global__ __launch_bounds__(256) void conv_kernel(
    const float* __restrict__ feats, const float* __restrict__ W,
    const int* __restrict__ in_map, const int* __restrict__ out_map,
    float* __restrict__ out, int M, int BPK)
{
    const int lane = threadIdx.x & 63;
    const int wv   = threadIdx.x >> 6;
    const int k    = blockIdx.x / BPK;
    const int blk  = blockIdx.x % BPK;
    const float* Wk = W + (size_t)k * 4096;
    float w[64];
#pragma unroll
    for (int c = 0; c < 64; ++c) w[c] = Wk[c * 64 + lane];
    __shared__ float fbuf[4][64];
    const int* im = in_map + (size_t)k * M;
    const int* om = out_map + (size_t)k * M;
    const int stride = BPK * 4;
    for (int m = blk * 4 + wv; m < M; m += stride) {
        int ii = im[m];
        int oi = om[m];
        float f = feats[(size_t)ii * 64 + lane];
        fbuf[wv][lane] = f;
        const float* fb = fbuf[wv];
        float a0 = 0.f, a1 = 0.f, a2 = 0.f, a3 = 0.f;
#pragma unroll
        for (int c = 0; c < 64; c += 4) {
            float4 f4 = *(const float4*)(fb + c);
            a0 = fmaf(f4.x, w[c + 0], a0);
            a1 = fmaf(f4.y, w[c + 1], a1);
            a2 = fmaf(f4.z, w[c + 2], a2);
            a3 = fmaf(f4.w, w[c + 3], a3);
        }
        unsafeAtomicAdd(out + (size_t)oi * 64 + lane, (a0 + a1) + (a2 + a3));
    }
}

__global__ __launch_bounds__(256) void gn_stats_kernel(
    const float4* __restrict__ x, float* __restrict__ stats, long total4)
{
    const int lane = threadIdx.x & 63;
    float s = 0.f, q = 0.f;
    const long stride = (long)gridDim.x * blockDim.x;
    for (long i = (long)blockIdx.x * blockDim.x + threadIdx.x; i < total4; i += stride) {
        float4 v = x[i];
        s += (v.x + v.y) + (v.z + v.w);
        q += (v.x * v.x + v.y * v.y) + (v.z * v.z + v.w * v.w);
    }
    s += __shfl_xor(s, 1);  q += __shfl_xor(q, 1);
    s += __shfl_xor(s, 16); q += __shfl_xor(q, 16);
    s += __shfl_xor(s, 32); q += __shfl_xor(q, 32);
    __shared__ float ls[4][16];
    const int wv = threadIdx.x >> 6;
    const int g = (lane >> 1) & 7;
    if (lane < 16 && (lane & 1) == 0) { ls[wv][g] = s; ls[wv][8 + g] = q; }
    __syncthreads();
    if (threadIdx.x < 16) {
        float t = (ls[0][threadIdx.x] + ls[1][threadIdx.x]) +
                  (ls[2][threadIdx.x] + ls[3][threadIdx.x]);
        unsafeAtomicAdd(stats + threadIdx.x, t);
    }
}

// ===========================================================================
// GroupNorm apply (+residual, +leaky); fp32 and/or bf16 outputs.
// ===========================================================================
__global__ __launch_bounds__(256) void gn_apply_kernel(
    const float4* __restrict__ x, const float* __restrict__ stats,
    const float* __restrict__ gamma, const float* __restrict__ beta,
    const float4* resid, float4* out_f, bf16x4* out_bf,
    long total4, float invc, int do_leaky)
{
    __shared__ float sc[64], sh[64];
    if (threadIdx.x < 64) {
        int c = threadIdx.x, g = c >> 3;
        float mean = stats[g] * invc;
        float var  = fmaf(-mean, mean, stats[8 + g] * invc);
        float s    = rsqrtf(var + GN_EPS) * gamma[c];
        sc[c] = s;
        sh[c] = fmaf(-mean, s, beta[c]);
    }
    __syncthreads();
    const long stride = (long)gridDim.x * blockDim.x;
    for (long i = (long)blockIdx.x * blockDim.x + threadIdx.x; i < total4; i += stride) {
        float4 v = x[i];
        int c0 = ((int)(i & 15)) << 2;
        float4 r;
        r.x = fmaf(v.x, sc[c0 + 0], sh[c0 + 0]);
        r.y = fmaf(v.y, sc[c0 + 1], sh[c0 + 1]);
        r.z = fmaf(v.z, sc[c0 + 2], sh[c0 + 2]);
        r.w = fmaf(v.w, sc[c0 + 3], sh[c0 + 3]);
        if (resid) {
            float4 h4 = resid[i];
            r.x += h4.x; r.y += h4.y; r.z += h4.z; r.w += h4.w;
        }
        if (do_leaky) {
            r.x = r.x >= 0.f ? r.x : NEG_SLOPE * r.x;
            r.y = r.y >= 0.f ? r.y : NEG_SLOPE * r.y;
            r.z = r.z >= 0.f ? r.z : NEG_SLOPE * r.z;
            r.w = r.w >= 0.f ? r.w : NEG_SLOPE * r.w;
        }
        if (out_f) out_f[i] = r;
        if (out_bf) {
            bf16x4 o;
            o.x = (__bf16)r.x; o.y = (__bf16)r.y; o.z = (__bf16)r.z; o.w = (__bf16)r.w;
            out_bf[i] = o;
        }
    }
}

// ===========================================================================
extern "C" void kernel_launch(void* const* d_in, const int* in_sizes, int n_in,
                              void* d_out, int out_size, void* d_ws, size_t ws_size,
                              hipStream_t stream) {
    const float* x   = (const float*)d_in[0];
    const float* W1  = (const float*)d_in[1];
    const float* g1  = (const float*)d_in[2];
    const float* b1  = (const float*)d_in[3];
    const float* Wa1 = (const float*)d_in[4];
    const float* ga1 = (const float*)d_in[5];
    const float* ba1 = (const float*)d_in[6];
    const float* Wb1 = (const float*)d_in[7];
    const float* gb1 = (const float*)d_in[8];
    const float* bb1 = (const float*)d_in[9];
    const float* Wa2 = (const float*)d_in[10];
    const float* ga2 = (const float*)d_in[11];
    const float* ba2 = (const float*)d_in[12];
    const float* Wb2 = (const float*)d_in[13];
    const float* gb2 = (const float*)d_in[14];
    const float* bb2 = (const float*)d_in[15];
    const int* m1_in  = (const int*)d_in[16];
    const int* m1_out = (const int*)d_in[17];
    const int* m2_in  = (const int*)d_in[18];
    const int* m2_out = (const int*)d_in[19];

    const int N   = out_size / 64;
    const int M1  = in_sizes[16] / 8;
    const int M2  = in_sizes[18] / 27;
    const int E1  = 8 * M1;
    const int E2  = 27 * M2;
    const int Emax = E1 > E2 ? E1 : E2;

    float* h = (float*)d_out;
    const long  total4 = (long)N * 16;
    const float invc   = 1.f / ((float)N * 8.f);

    // ---- workspace layout (256B aligned) ----
    char* wp = (char*)d_ws;
    size_t off = 0;
    auto alloc = [&](size_t bytes) {
        void* p = wp + off;
        off = (off + bytes + 255) & ~(size_t)255;
        return p;
    };
    float*  accA  = (float*)alloc((size_t)N * 64 * 4);
    float*  accB  = (float*)alloc((size_t)N * 64 * 4);
    __bf16* hbf   = (__bf16*)alloc((size_t)N * 64 * 2);
    __bf16* Cbuf  = (__bf16*)alloc((size_t)Emax * 64 * 2);
    int*    base1 = (int*)alloc((size_t)(N + 1) * 4);
    int*    base2 = (int*)alloc((size_t)(N + 1) * 4);
    int*    cnt   = (int*)alloc((size_t)N * 4);
    int*    part  = (int*)alloc(4096);
    int*    inv1  = (int*)alloc((size_t)E1 * 4);
    int*    inv2  = (int*)alloc((size_t)E2 * 4);
    float*  stats = (float*)alloc(5 * 16 * 4);   // st0, stA1, stB1, stA2, stB2
    const size_t need = off;

    if (ws_size < need) {
        // -------- legacy atomic fallback --------
        float* y  = accB;
        float* st = stats;
        const size_t nbytes = (size_t)N * 64 * 4;
        auto convL = [&](const float* feats, const float* W, const int* im,
                         const int* om, int K, int M, int BPK) {
            hipMemsetAsync(accA, 0, nbytes, stream);
            conv_kernel<<<dim3(K * BPK), 256, 0, stream>>>(feats, W, im, om, accA, M, BPK);
        };
        auto gnL = [&](const float* gamma, const float* beta, const float* resid,
                       float* outp, int leaky) {
            hipMemsetAsync(st, 0, 16 * sizeof(float), stream);
            gn_stats_kernel<<<1024, 256, 0, stream>>>((const float4*)accA, st, total4);
            gn_apply_kernel<<<1024, 256, 0, stream>>>((const float4*)accA, st, gamma, beta,
                                                      (const float4*)resid, (float4*)outp,
                                                      nullptr, total4, invc, leaky);
        };
        convL(x, W1, m1_in, m1_out, 8, M1, 320); gnL(g1, b1, nullptr, h, 1);
        convL(h, Wa1, m2_in, m2_out, 27, M2, 96); gnL(ga1, ba1, nullptr, y, 0);
        convL(y, Wb1, m2_in, m2_out, 27, M2, 96); gnL(gb1, bb1, h, h, 1);
        convL(h, Wa2, m2_in, m2_out, 27, M2, 96); gnL(ga2, ba2, nullptr, y, 0);
        convL(y, Wb2, m2_in, m2_out, 27, M2, 96); gnL(gb2, bb2, h, h, 1);
        return;
    }

    // -------- MFMA + sorted-streaming-reduce path --------
    hipMemsetAsync(stats, 0, 5 * 16 * sizeof(float), stream);   // all stat slots

    const int nb = (N + 1023) / 1024;
    auto buildCSR = [&](const int* om, int E, int* base, int* inv) {
        hipMemsetAsync(cnt, 0, (size_t)N * 4, stream);
        hist_kernel<<<2048, 256, 0, stream>>>(om, cnt, E);
        scan1_kernel<<<nb, 256, 0, stream>>>(cnt, part, N);
        scan2_kernel<<<1, 64, 0, stream>>>(part, nb);
        scan3_kernel<<<nb, 256, 0, stream>>>(cnt, part, base, N);
        hipMemsetAsync(cnt, 0, (size_t)N * 4, stream);
        scatter_kernel<<<2048, 256, 0, stream>>>(om, base, cnt, inv, E);
    };
    buildCSR(m1_out, E1, base1, inv1);
    buildCSR(m2_out, E2, base2, inv2);

    float* st0  = stats;
    float* stA1 = stats + 16;
    float* stB1 = stats + 32;
    float* stA2 = stats + 48;
    float* stB2 = stats + 64;

    // variant = 0: bf16 gather, no norm; 1: fp32 gather, no norm; 2: fp32+NORM
    auto conv = [&](const void* feats, int variant, const float* W, const int* im,
                    int K, int M, int BPK, const int* base, const int* inv,
                    float* accOut, float* statOut,
                    const float* nstats, const float* ngamma, const float* nbeta) {
        dim3 grid(K * BPK);
        if (variant == 2)
            conv_mfma_kernel<1, 1><<<grid, 256, 0, stream>>>(feats, W, im, inv, Cbuf,
                M, BPK, nstats, ngamma, nbeta, invc);
        else if (variant == 1)
            conv_mfma_kernel<1, 0><<<grid, 256, 0, stream>>>(feats, W, im, inv, Cbuf,
                M, BPK, nullptr, nullptr, nullptr, invc);
        else
            conv_mfma_kernel<0, 0><<<grid, 256, 0, stream>>>(feats, W, im, inv, Cbuf,
                M, BPK, nullptr, nullptr, nullptr, invc);
        reduce_kernel<<<2048, 256, 0, stream>>>((const unsigned*)Cbuf, base,
                                                accOut, statOut, N);
    };
    auto gn = [&](const float* src, const float* st, const float* gamma,
                  const float* beta, const float* resid, float* outf,
                  __bf16* outbf, int leaky) {
        gn_apply_kernel<<<1024, 256, 0, stream>>>((const float4*)src, st, gamma, beta,
                                                  (const float4*)resid, (float4*)outf,
                                                  (bf16x4*)outbf, total4, invc, leaky);
    };

    // BasicConvolutionBlock
    conv(x, 1, W1, m1_in, 8, M1, 128, base1, inv1, accA, st0, nullptr, nullptr, nullptr);
    gn(accA, st0, g1, b1, nullptr, h, hbf, 1);
    // ResidualBlock 1: y = GN(conv_a(h)) applied inside conv_b's gather
    conv(hbf, 0, Wa1, m2_in, 27, M2, 64, base2, inv2, accA, stA1, nullptr, nullptr, nullptr);
    conv(accA, 2, Wb1, m2_in, 27, M2, 64, base2, inv2, accB, stB1, stA1, ga1, ba1);
    gn(accB, stB1, gb1, bb1, h, h, hbf, 1);
    // ResidualBlock 2
    conv(hbf, 0, Wa2, m2_in, 27, M2, 64, base2, inv2, accA, stA2, nullptr, nullptr, nullptr);
    conv(accA, 2, Wb2, m2_in, 27, M2, 64, base2, inv2, accB, stB2, stA2, ga2, ba2);
    gn(accB, stB2, gb2, bb2, h, h, nullptr, 1);
}

// Round 10
// 1078.287 us; speedup vs baseline: 1.1783x; 1.0884x over previous
//
#include <hip/hip_runtime.h>

#define NEG_SLOPE 0.01f
#define GN_EPS 1e-5f

typedef __attribute__((ext_vector_type(8))) __bf16 bf16x8;
typedef __attribute__((ext_vector_type(4))) __bf16 bf16x4;
typedef __attribute__((ext_vector_type(4))) float f32x4;
typedef __attribute__((ext_vector_type(2))) unsigned uintx2;

__device__ __forceinline__ float bf_lo(unsigned v) { return __uint_as_float(v << 16); }
__device__ __forceinline__ float bf_hi(unsigned v) { return __uint_as_float(v & 0xffff0000u); }

// ===========================================================================
// CSR build: histogram -> 2-level exclusive scan -> inverse-permutation scatter
// ===========================================================================
__global__ __launch_bounds__(256) void hist_kernel(
    const int* __restrict__ om, int* __restrict__ cnt, int E)
{
    const int stride = gridDim.x * blockDim.x;
    for (int e = blockIdx.x * blockDim.x + threadIdx.x; e < E; e += stride)
        atomicAdd(&cnt[om[e]], 1);
}

__global__ __launch_bounds__(256) void scan1_kernel(
    const int* __restrict__ cnt, int* __restrict__ part, int N)
{
    __shared__ int ls[256];
    int b = blockIdx.x, t = threadIdx.x;
    int i0 = b * 1024 + t * 4, s = 0;
#pragma unroll
    for (int u = 0; u < 4; ++u) if (i0 + u < N) s += cnt[i0 + u];
    ls[t] = s; __syncthreads();
    for (int off = 128; off > 0; off >>= 1) {
        if (t < off) ls[t] += ls[t + off];
        __syncthreads();
    }
    if (t == 0) part[b] = ls[0];
}

__global__ void scan2_kernel(int* __restrict__ part, int nb)
{
    if (blockIdx.x == 0 && threadIdx.x == 0) {
        int run = 0;
        for (int i = 0; i < nb; ++i) { int v = part[i]; part[i] = run; run += v; }
    }
}

__global__ __launch_bounds__(256) void scan3_kernel(
    const int* __restrict__ cnt, const int* __restrict__ part,
    int* __restrict__ base, int N)
{
    __shared__ int ls[256];
    int b = blockIdx.x, t = threadIdx.x;
    int i0 = b * 1024 + t * 4;
    int v0 = 0, v1 = 0, v2 = 0, v3 = 0;
    if (i0 + 0 < N) v0 = cnt[i0 + 0];
    if (i0 + 1 < N) v1 = cnt[i0 + 1];
    if (i0 + 2 < N) v2 = cnt[i0 + 2];
    if (i0 + 3 < N) v3 = cnt[i0 + 3];
    int s = v0 + v1 + v2 + v3;
    ls[t] = s; __syncthreads();
    for (int off = 1; off < 256; off <<= 1) {
        int x = (t >= off) ? ls[t - off] : 0;
        __syncthreads();
        ls[t] += x;
        __syncthreads();
    }
    int run = part[b] + ls[t] - s;   // exclusive prefix
    if (i0 + 0 < N) { base[i0 + 0] = run; run += v0; if (i0 + 0 == N - 1) base[N] = run; }
    if (i0 + 1 < N) { base[i0 + 1] = run; run += v1; if (i0 + 1 == N - 1) base[N] = run; }
    if (i0 + 2 < N) { base[i0 + 2] = run; run += v2; if (i0 + 2 == N - 1) base[N] = run; }
    if (i0 + 3 < N) { base[i0 + 3] = run; run += v3; if (i0 + 3 == N - 1) base[N] = run; }
}

__global__ __launch_bounds__(256) void scatter_kernel(
    const int* __restrict__ om, const int* __restrict__ base,
    int* __restrict__ cur, int* __restrict__ inv, int E)
{
    const int stride = gridDim.x * blockDim.x;
    for (int e = blockIdx.x * blockDim.x + threadIdx.x; e < E; e += stride) {
        int o = om[e];
        int p = base[o] + atomicAdd(&cur[o], 1);
        inv[e] = p;           // edge e's row lands at sorted position p
    }
}

// ===========================================================================
// Phase A: per-offset GEMM via bf16 MFMA (round-7 orientation: D row=edge,
// col=channel; lane-quarter emits each row as 4 consecutive 32B pieces ->
// write-combine merges to full lines, WRITE_SIZE == |C|). C row for edge e
// goes to sorted position inv[e]; non-temporal (read once by reduce).
// ===========================================================================
template<int F32IN>
__global__ __launch_bounds__(256) void conv_mfma_kernel(
    const void* __restrict__ feats, const float* __restrict__ W,
    const int* __restrict__ in_map, const int* __restrict__ inv,
    __bf16* __restrict__ C, int M, int BPK)
{
    const int lane = threadIdx.x & 63;
    const int wv   = threadIdx.x >> 6;
    const int k    = blockIdx.x / BPK;
    const int blk  = blockIdx.x % BPK;
    const int l15  = lane & 15;
    const int lg   = lane >> 4;         // 0..3

    // B fragments: b[nt][h] covers cols nt*16+l15, K-half h
    const float* Wk = W + (size_t)k * 4096;
    bf16x8 b[4][2];
#pragma unroll
    for (int nt = 0; nt < 4; ++nt)
#pragma unroll
        for (int h = 0; h < 2; ++h)
#pragma unroll
            for (int j = 0; j < 8; ++j)
                b[nt][h][j] = (__bf16)Wk[(h * 32 + lg * 8 + j) * 64 + nt * 16 + l15];

    const int* imk   = in_map + (size_t)k * M;
    const int ntiles = (M + 15) >> 4;
    const int wpk    = BPK * 4;

    for (int t = blk * 4 + wv; t < ntiles; t += wpk) {
        int m  = t * 16 + l15;
        int mc = m < M ? m : M - 1;
        int ii = imk[mc];
        bf16x8 a0, a1;
        if (F32IN) {
            const float4* rp = (const float4*)((const float*)feats + (size_t)ii * 64 + lg * 8);
            float4 u0 = rp[0], u1 = rp[1];
            float4 u2 = rp[8], u3 = rp[9];   // +32 channels
            a0[0] = (__bf16)u0.x; a0[1] = (__bf16)u0.y; a0[2] = (__bf16)u0.z; a0[3] = (__bf16)u0.w;
            a0[4] = (__bf16)u1.x; a0[5] = (__bf16)u1.y; a0[6] = (__bf16)u1.z; a0[7] = (__bf16)u1.w;
            a1[0] = (__bf16)u2.x; a1[1] = (__bf16)u2.y; a1[2] = (__bf16)u2.z; a1[3] = (__bf16)u2.w;
            a1[4] = (__bf16)u3.x; a1[5] = (__bf16)u3.y; a1[6] = (__bf16)u3.z; a1[7] = (__bf16)u3.w;
        } else {
            const bf16x8* rp = (const bf16x8*)((const __bf16*)feats + (size_t)ii * 64 + lg * 8);
            a0 = rp[0];
            a1 = rp[4];   // +32 channels
        }
        f32x4 c0 = {0.f,0.f,0.f,0.f}, c1 = c0, c2 = c0, c3 = c0;
        c0 = __builtin_amdgcn_mfma_f32_16x16x32_bf16(a0, b[0][0], c0, 0, 0, 0);
        c1 = __builtin_amdgcn_mfma_f32_16x16x32_bf16(a0, b[1][0], c1, 0, 0, 0);
        c2 = __builtin_amdgcn_mfma_f32_16x16x32_bf16(a0, b[2][0], c2, 0, 0, 0);
        c3 = __builtin_amdgcn_mfma_f32_16x16x32_bf16(a0, b[3][0], c3, 0, 0, 0);
        c0 = __builtin_amdgcn_mfma_f32_16x16x32_bf16(a1, b[0][1], c0, 0, 0, 0);
        c1 = __builtin_amdgcn_mfma_f32_16x16x32_bf16(a1, b[1][1], c1, 0, 0, 0);
        c2 = __builtin_amdgcn_mfma_f32_16x16x32_bf16(a1, b[2][1], c2, 0, 0, 0);
        c3 = __builtin_amdgcn_mfma_f32_16x16x32_bf16(a1, b[3][1], c3, 0, 0, 0);

        const int e_base = k * M + t * 16;
        f32x4 cc[4] = {c0, c1, c2, c3};
#pragma unroll
        for (int r = 0; r < 4; ++r) {
            int row = lg * 4 + r;
            if (t * 16 + row < M) {
                int p = inv[e_base + row];            // broadcast within l15-group
                __bf16* cr = C + (size_t)p * 64 + l15;
#pragma unroll
                for (int nt = 0; nt < 4; ++nt) {
                    __bf16 v = (__bf16)cc[nt][r];
                    __builtin_nontemporal_store(v, cr + nt * 16);
                }
            }
        }
    }
}

// ===========================================================================
// Phase B: segmented streaming reduce + FUSED GroupNorm stats. One wave per
// output row per iter; 4 rows/instruction: lane = (row l>>4) x (channel quad
// l&15, 8B uintx2 load). 16 lanes store float4 per row. Per-wave stat regs
// -> block LDS combine -> 16 global atomics per block.
// ===========================================================================
__global__ __launch_bounds__(256) void reduce_kernel(
    const unsigned* __restrict__ C2, const int* __restrict__ base,
    float* __restrict__ out, float* __restrict__ stats, int N)
{
    const int lane = threadIdx.x & 63;
    const int wv   = threadIdx.x >> 6;
    const int rq   = lane >> 4;       // row offset 0..3
    const int cq   = lane & 15;       // channel quad: channels cq*4 .. cq*4+3
    float rs = 0.f, rqsum = 0.f;

    const int ostride = gridDim.x * 4;
    for (int o = blockIdx.x * 4 + wv; o < N; o += ostride) {
        const int s = base[o], t = base[o + 1];
        float a0 = 0.f, a1 = 0.f, a2 = 0.f, a3 = 0.f;
        for (int i = s + rq; i < t; i += 4) {
            uintx2 v = __builtin_nontemporal_load(
                (const uintx2*)(C2 + (size_t)i * 32 + cq * 2));
            a0 += bf_lo(v.x); a1 += bf_hi(v.x);
            a2 += bf_lo(v.y); a3 += bf_hi(v.y);
        }
        a0 += __shfl_xor(a0, 16); a1 += __shfl_xor(a1, 16);
        a2 += __shfl_xor(a2, 16); a3 += __shfl_xor(a3, 16);
        a0 += __shfl_xor(a0, 32); a1 += __shfl_xor(a1, 32);
        a2 += __shfl_xor(a2, 32); a3 += __shfl_xor(a3, 32);
        if (rq == 0) {
            float4 r = {a0, a1, a2, a3};
            *(float4*)(out + (size_t)o * 64 + cq * 4) = r;
            rs    += (a0 + a1) + (a2 + a3);
            rqsum += (a0 * a0 + a1 * a1) + (a2 * a2 + a3 * a3);
        }
    }
    // lanes rq==0: channel quad cq belongs to group g = cq>>1; combine pairs
    rs += __shfl_xor(rs, 1); rqsum += __shfl_xor(rqsum, 1);
    __shared__ float ls[4][16];
    if (rq == 0 && (cq & 1) == 0) {
        ls[wv][cq >> 1] = rs;
        ls[wv][8 + (cq >> 1)] = rqsum;
    }
    __syncthreads();
    if (threadIdx.x < 16) {
        float t = (ls[0][threadIdx.x] + ls[1][threadIdx.x]) +
                  (ls[2][threadIdx.x] + ls[3][threadIdx.x]);
        unsafeAtomicAdd(stats + threadIdx.x, t);
    }
}

// ===========================================================================
// Legacy atomic-scatter conv + standalone gn_stats (ws_size fallback path)
// ===========================================================================
__global__ __launch_bounds__(256) void conv_kernel(
    const float* __restrict__ feats, const float* __restrict__ W,
    const int* __restrict__ in_map, const int* __restrict__ out_map,
    float* __restrict__ out, int M, int BPK)
{
    const int lane = threadIdx.x & 63;
    const int wv   = threadIdx.x >> 6;
    const int k    = blockIdx.x / BPK;
    const int blk  = blockIdx.x % BPK;
    const float* Wk = W + (size_t)k * 4096;
    float w[64];
#pragma unroll
    for (int c = 0; c < 64; ++c) w[c] = Wk[c * 64 + lane];
    __shared__ float fbuf[4][64];
    const int* im = in_map + (size_t)k * M;
    const int* om = out_map + (size_t)k * M;
    const int stride = BPK * 4;
    for (int m = blk * 4 + wv; m < M; m += stride) {
        int ii = im[m];
        int oi = om[m];
        float f = feats[(size_t)ii * 64 + lane];
        fbuf[wv][lane] = f;
        const float* fb = fbuf[wv];
        float a0 = 0.f, a1 = 0.f, a2 = 0.f, a3 = 0.f;
#pragma unroll
        for (int c = 0; c < 64; c += 4) {
            float4 f4 = *(const float4*)(fb + c);
            a0 = fmaf(f4.x, w[c + 0], a0);
            a1 = fmaf(f4.y, w[c + 1], a1);
            a2 = fmaf(f4.z, w[c + 2], a2);
            a3 = fmaf(f4.w, w[c + 3], a3);
        }
        unsafeAtomicAdd(out + (size_t)oi * 64 + lane, (a0 + a1) + (a2 + a3));
    }
}

__global__ __launch_bounds__(256) void gn_stats_kernel(
    const float4* __restrict__ x, float* __restrict__ stats, long total4)
{
    const int lane = threadIdx.x & 63;
    float s = 0.f, q = 0.f;
    const long stride = (long)gridDim.x * blockDim.x;
    for (long i = (long)blockIdx.x * blockDim.x + threadIdx.x; i < total4; i += stride) {
        float4 v = x[i];
        s += (v.x + v.y) + (v.z + v.w);
        q += (v.x * v.x + v.y * v.y) + (v.z * v.z + v.w * v.w);
    }
    s += __shfl_xor(s, 1);  q += __shfl_xor(q, 1);
    s += __shfl_xor(s, 16); q += __shfl_xor(q, 16);
    s += __shfl_xor(s, 32); q += __shfl_xor(q, 32);
    __shared__ float ls[4][16];
    const int wv = threadIdx.x >> 6;
    const int g = (lane >> 1) & 7;
    if (lane < 16 && (lane & 1) == 0) { ls[wv][g] = s; ls[wv][8 + g] = q; }
    __syncthreads();
    if (threadIdx.x < 16) {
        float t = (ls[0][threadIdx.x] + ls[1][threadIdx.x]) +
                  (ls[2][threadIdx.x] + ls[3][threadIdx.x]);
        unsafeAtomicAdd(stats + threadIdx.x, t);
    }
}

// ===========================================================================
// GroupNorm apply (+residual, +leaky); fp32 and/or bf16 outputs.
// ===========================================================================
__global__ __launch_bounds__(256) void gn_apply_kernel(
    const float4* __restrict__ x, const float* __restrict__ stats,
    const float* __restrict__ gamma, const float* __restrict__ beta,
    const float4* resid, float4* out_f, bf16x4* out_bf,
    long total4, float invc, int do_leaky)
{
    __shared__ float sc[64], sh[64];
    if (threadIdx.x < 64) {
        int c = threadIdx.x, g = c >> 3;
        float mean = stats[g] * invc;
        float var  = fmaf(-mean, mean, stats[8 + g] * invc);
        float s    = rsqrtf(var + GN_EPS) * gamma[c];
        sc[c] = s;
        sh[c] = fmaf(-mean, s, beta[c]);
    }
    __syncthreads();
    const long stride = (long)gridDim.x * blockDim.x;
    for (long i = (long)blockIdx.x * blockDim.x + threadIdx.x; i < total4; i += stride) {
        float4 v = x[i];
        int c0 = ((int)(i & 15)) << 2;
        float4 r;
        r.x = fmaf(v.x, sc[c0 + 0], sh[c0 + 0]);
        r.y = fmaf(v.y, sc[c0 + 1], sh[c0 + 1]);
        r.z = fmaf(v.z, sc[c0 + 2], sh[c0 + 2]);
        r.w = fmaf(v.w, sc[c0 + 3], sh[c0 + 3]);
        if (resid) {
            float4 h4 = resid[i];
            r.x += h4.x; r.y += h4.y; r.z += h4.z; r.w += h4.w;
        }
        if (do_leaky) {
            r.x = r.x >= 0.f ? r.x : NEG_SLOPE * r.x;
            r.y = r.y >= 0.f ? r.y : NEG_SLOPE * r.y;
            r.z = r.z >= 0.f ? r.z : NEG_SLOPE * r.z;
            r.w = r.w >= 0.f ? r.w : NEG_SLOPE * r.w;
        }
        if (out_f) out_f[i] = r;
        if (out_bf) {
            bf16x4 o;
            o.x = (__bf16)r.x; o.y = (__bf16)r.y; o.z = (__bf16)r.z; o.w = (__bf16)r.w;
            out_bf[i] = o;
        }
    }
}

// ===========================================================================
extern "C" void kernel_launch(void* const* d_in, const int* in_sizes, int n_in,
                              void* d_out, int out_size, void* d_ws, size_t ws_size,
                              hipStream_t stream) {
    const float* x   = (const float*)d_in[0];
    const float* W1  = (const float*)d_in[1];
    const float* g1  = (const float*)d_in[2];
    const float* b1  = (const float*)d_in[3];
    const float* Wa1 = (const float*)d_in[4];
    const float* ga1 = (const float*)d_in[5];
    const float* ba1 = (const float*)d_in[6];
    const float* Wb1 = (const float*)d_in[7];
    const float* gb1 = (const float*)d_in[8];
    const float* bb1 = (const float*)d_in[9];
    const float* Wa2 = (const float*)d_in[10];
    const float* ga2 = (const float*)d_in[11];
    const float* ba2 = (const float*)d_in[12];
    const float* Wb2 = (const float*)d_in[13];
    const float* gb2 = (const float*)d_in[14];
    const float* bb2 = (const float*)d_in[15];
    const int* m1_in  = (const int*)d_in[16];
    const int* m1_out = (const int*)d_in[17];
    const int* m2_in  = (const int*)d_in[18];
    const int* m2_out = (const int*)d_in[19];

    const int N   = out_size / 64;
    const int M1  = in_sizes[16] / 8;
    const int M2  = in_sizes[18] / 27;
    const int E1  = 8 * M1;
    const int E2  = 27 * M2;
    const int Emax = E1 > E2 ? E1 : E2;

    float* h = (float*)d_out;
    const long  total4 = (long)N * 16;
    const float invc   = 1.f / ((float)N * 8.f);

    // ---- workspace layout (256B aligned) ----
    char* wp = (char*)d_ws;
    size_t off = 0;
    auto alloc = [&](size_t bytes) {
        void* p = wp + off;
        off = (off + bytes + 255) & ~(size_t)255;
        return p;
    };
    float*  acc   = (float*)alloc((size_t)N * 64 * 4);
    __bf16* hbf   = (__bf16*)alloc((size_t)N * 64 * 2);
    __bf16* ybf   = (__bf16*)alloc((size_t)N * 64 * 2);
    __bf16* Cbuf  = (__bf16*)alloc((size_t)Emax * 64 * 2);
    int*    base1 = (int*)alloc((size_t)(N + 1) * 4);
    int*    base2 = (int*)alloc((size_t)(N + 1) * 4);
    int*    cnt   = (int*)alloc((size_t)N * 4);
    int*    part  = (int*)alloc(4096);
    int*    inv1  = (int*)alloc((size_t)E1 * 4);
    int*    inv2  = (int*)alloc((size_t)E2 * 4);
    float*  stats = (float*)alloc(5 * 16 * 4);   // st0, stA1, stB1, stA2, stB2
    const size_t need = off;

    if (ws_size < need) {
        // -------- legacy atomic fallback --------
        float* y  = (float*)Cbuf;   // reuse region (>= N*64*4 bytes)
        float* st = stats;
        const size_t nbytes = (size_t)N * 64 * 4;
        auto convL = [&](const float* feats, const float* W, const int* im,
                         const int* om, int K, int M, int BPK) {
            hipMemsetAsync(acc, 0, nbytes, stream);
            conv_kernel<<<dim3(K * BPK), 256, 0, stream>>>(feats, W, im, om, acc, M, BPK);
        };
        auto gnL = [&](const float* gamma, const float* beta, const float* resid,
                       float* outp, int leaky) {
            hipMemsetAsync(st, 0, 16 * sizeof(float), stream);
            gn_stats_kernel<<<1024, 256, 0, stream>>>((const float4*)acc, st, total4);
            gn_apply_kernel<<<1024, 256, 0, stream>>>((const float4*)acc, st, gamma, beta,
                                                      (const float4*)resid, (float4*)outp,
                                                      nullptr, total4, invc, leaky);
        };
        convL(x, W1, m1_in, m1_out, 8, M1, 320); gnL(g1, b1, nullptr, h, 1);
        convL(h, Wa1, m2_in, m2_out, 27, M2, 96); gnL(ga1, ba1, nullptr, y, 0);
        convL(y, Wb1, m2_in, m2_out, 27, M2, 96); gnL(gb1, bb1, h, h, 1);
        convL(h, Wa2, m2_in, m2_out, 27, M2, 96); gnL(ga2, ba2, nullptr, y, 0);
        convL(y, Wb2, m2_in, m2_out, 27, M2, 96); gnL(gb2, bb2, h, h, 1);
        return;
    }

    // -------- MFMA + sorted-streaming-reduce path --------
    hipMemsetAsync(stats, 0, 5 * 16 * sizeof(float), stream);   // all stat slots

    const int nb = (N + 1023) / 1024;
    auto buildCSR = [&](const int* om, int E, int* base, int* inv) {
        hipMemsetAsync(cnt, 0, (size_t)N * 4, stream);
        hist_kernel<<<2048, 256, 0, stream>>>(om, cnt, E);
        scan1_kernel<<<nb, 256, 0, stream>>>(cnt, part, N);
        scan2_kernel<<<1, 64, 0, stream>>>(part, nb);
        scan3_kernel<<<nb, 256, 0, stream>>>(cnt, part, base, N);
        hipMemsetAsync(cnt, 0, (size_t)N * 4, stream);
        scatter_kernel<<<2048, 256, 0, stream>>>(om, base, cnt, inv, E);
    };
    buildCSR(m1_out, E1, base1, inv1);
    buildCSR(m2_out, E2, base2, inv2);

    float* st0  = stats;
    float* stA1 = stats + 16;
    float* stB1 = stats + 32;
    float* stA2 = stats + 48;
    float* stB2 = stats + 64;

    auto conv = [&](const void* feats, int f32in, const float* W, const int* im,
                    int K, int M, int BPK, const int* base, const int* inv,
                    float* statOut) {
        dim3 grid(K * BPK);
        if (f32in)
            conv_mfma_kernel<1><<<grid, 256, 0, stream>>>(feats, W, im, inv, Cbuf, M, BPK);
        else
            conv_mfma_kernel<0><<<grid, 256, 0, stream>>>(feats, W, im, inv, Cbuf, M, BPK);
        reduce_kernel<<<2048, 256, 0, stream>>>((const unsigned*)Cbuf, base,
                                                acc, statOut, N);
    };
    auto gn = [&](const float* st, const float* gamma, const float* beta,
                  const float* resid, float* outf, __bf16* outbf, int leaky) {
        gn_apply_kernel<<<1024, 256, 0, stream>>>((const float4*)acc, st, gamma, beta,
                                                  (const float4*)resid, (float4*)outf,
                                                  (bf16x4*)outbf, total4, invc, leaky);
    };

    // BasicConvolutionBlock (gathers fp32 x directly)
    conv(x, 1, W1, m1_in, 8, M1, 256, base1, inv1, st0);
    gn(st0, g1, b1, nullptr, h, hbf, 1);
    // ResidualBlock 1
    conv(hbf, 0, Wa1, m2_in, 27, M2, 96, base2, inv2, stA1);
    gn(stA1, ga1, ba1, nullptr, nullptr, ybf, 0);
    conv(ybf, 0, Wb1, m2_in, 27, M2, 96, base2, inv2, stB1);
    gn(stB1, gb1, bb1, h, h, hbf, 1);
    // ResidualBlock 2
    conv(hbf, 0, Wa2, m2_in, 27, M2, 96, base2, inv2, stA2);
    gn(stA2, ga2, ba2, nullptr, nullptr, ybf, 0);
    conv(ybf, 0, Wb2, m2_in, 27, M2, 96, base2, inv2, stB2);
    gn(stB2, gb2, bb2, h, h, nullptr, 1);
}